// Round 2
// baseline (512.472 us; speedup 1.0000x reference)
//
#include <hip/hip_runtime.h>
#include <math.h>

#define BB 4
#define C 64
#define O 64
#define H 128
#define W 128
#define OG 2
#define Cg 32
#define K2 9
#define HW (H*W)
#define NOFF 36   /* 2*OG*K2 offset channels */
#define NMSK 18   /* OG*K2 mask channels */
#define NC 54     /* NOFF+NMSK */
#define JT 18     /* output channels per block in conv_offmask (54/3) */
#define OT 16     /* output channels per block in deform (64/4) */

// ---------------------------------------------------------------------------
// Weight re-layout:
//  wcomb[c][tap][j] (j<36: offset conv weights, j>=36: mask conv weights)
//    -> inner j-loop reads contiguous floats at block-uniform address (s_load)
//  wt[g][k][c][o] -> inner o-loop reads contiguous floats at uniform addr
// ---------------------------------------------------------------------------
__global__ __launch_bounds__(256) void prep_weights(
    const float* __restrict__ w_main, const float* __restrict__ w_off,
    const float* __restrict__ w_mask, float* __restrict__ wcomb,
    float* __restrict__ wt) {
  int i = blockIdx.x * 256 + threadIdx.x;
  const int NW1 = C * K2 * NC;        // 31104
  const int NW2 = OG * K2 * Cg * O;   // 36864
  if (i < NW1) {
    int j = i % NC;
    int ct = i / NC;
    int tap = ct % K2;
    int c = ct / K2;
    float v = (j < NOFF) ? w_off[(j * C + c) * K2 + tap]
                         : w_mask[((j - NOFF) * C + c) * K2 + tap];
    wcomb[i] = v;
  } else if (i < NW1 + NW2) {
    int t = i - NW1;
    int o = t % O;
    int r = t / O;           // r = (g*9+k)*32 + c
    int c = r % Cg;
    int gk = r / Cg;         // g*9+k
    int g = gk / K2;
    int k = gk % K2;
    wt[t] = w_main[(o * C + g * Cg + c) * K2 + k];
  }
}

// ---------------------------------------------------------------------------
// Offset/mask 3x3 conv, thread-per-pixel, output-channel-split 3 ways.
// blockIdx.x: 256 pixel tiles (64x4 per block); blockIdx.y: jgroup 0..2.
// jg 0/1 -> offset channels [18*jg, 18*jg+18); jg 2 -> all 18 mask channels.
// ---------------------------------------------------------------------------
__global__ __launch_bounds__(256) void conv_offmask(
    const float* __restrict__ x, const float* __restrict__ wcomb,
    const float* __restrict__ b_off, const float* __restrict__ b_mask,
    float* __restrict__ offs, float* __restrict__ msk) {
  int lane = threadIdx.x;
  int w = (blockIdx.x & 1) * 64 + (lane & 63);
  int h = ((blockIdx.x >> 1) & 31) * 4 + (lane >> 6);
  int b = blockIdx.x >> 6;
  int jg = blockIdx.y;

  float acc[JT];
#pragma unroll
  for (int j = 0; j < JT; j++) acc[j] = 0.f;

  const float* xb = x + b * C * HW;
#pragma unroll 2
  for (int c = 0; c < C; c++) {
    const float* xc = xb + c * HW;
    float xv[9];
#pragma unroll
    for (int dy = 0; dy < 3; dy++) {
      int yy = h + dy - 1;
      bool yok = (unsigned)yy < (unsigned)H;
#pragma unroll
      for (int dx = 0; dx < 3; dx++) {
        int xx = w + dx - 1;
        bool ok = yok && ((unsigned)xx < (unsigned)W);
        xv[dy * 3 + dx] = ok ? xc[yy * W + xx] : 0.f;
      }
    }
    const float* wr = wcomb + c * K2 * NC + jg * JT;
#pragma unroll
    for (int t = 0; t < 9; t++) {
#pragma unroll
      for (int j = 0; j < JT; j++) acc[j] += xv[t] * wr[t * NC + j];
    }
  }

  int pix = h * W + w;
  if (jg < 2) {
    int j0 = jg * JT;
#pragma unroll
    for (int j = 0; j < JT; j++)
      offs[(b * NOFF + j0 + j) * HW + pix] = acc[j] + b_off[j0 + j];
  } else {
#pragma unroll
    for (int j = 0; j < JT; j++) {
      float v = acc[j] + b_mask[j];
      msk[(b * NMSK + j) * HW + pix] = 1.f / (1.f + __expf(-v));
    }
  }
}

// ---------------------------------------------------------------------------
// Deformable conv main kernel, thread-per-pixel, output-channel-split 4 ways.
// blockIdx.x: 256 pixel tiles; blockIdx.y: ogroup 0..3 -> o in [16*og,16*og+16)
// Sampling work (4 gathers + corner weights) duplicated across ogroups; the
// 16-waves/CU occupancy hides the gather latency that dominated round 1.
// ---------------------------------------------------------------------------
__global__ __launch_bounds__(256) void deform(
    const float* __restrict__ x, const float* __restrict__ wt,
    const float* __restrict__ offs, const float* __restrict__ msk,
    float* __restrict__ out) {
  int lane = threadIdx.x;
  int w = (blockIdx.x & 1) * 64 + (lane & 63);
  int h = ((blockIdx.x >> 1) & 31) * 4 + (lane >> 6);
  int b = blockIdx.x >> 6;
  int og = blockIdx.y;
  int pix = h * W + w;

  float acc[OT];
#pragma unroll
  for (int o = 0; o < OT; o++) acc[o] = 0.f;

#pragma unroll 1
  for (int g = 0; g < OG; g++) {
    const float* xg = x + (b * C + g * Cg) * HW;
#pragma unroll 1
    for (int k = 0; k < K2; k++) {
      int gk = g * K2 + k;
      float offy = offs[(b * NOFF + gk * 2) * HW + pix];
      float offx = offs[(b * NOFF + gk * 2 + 1) * HW + pix];
      float m = msk[(b * NMSK + gk) * HW + pix];

      float py = offy + (float)(h - 1 + k / 3);
      float px = offx + (float)(w - 1 + k % 3);
      float y0f = floorf(py), x0f = floorf(px);
      float wy1 = py - y0f, wx1 = px - x0f;
      float wy0 = 1.f - wy1, wx0 = 1.f - wx1;
      int y0 = (int)y0f, x0 = (int)x0f;
      int y1 = y0 + 1, x1 = x0 + 1;
      bool y0ok = (unsigned)y0 < (unsigned)H, y1ok = (unsigned)y1 < (unsigned)H;
      bool x0ok = (unsigned)x0 < (unsigned)W, x1ok = (unsigned)x1 < (unsigned)W;
      // fold validity and mask into the 4 corner weights (once per (g,k))
      float w00 = (y0ok && x0ok) ? wy0 * wx0 * m : 0.f;
      float w01 = (y0ok && x1ok) ? wy0 * wx1 * m : 0.f;
      float w10 = (y1ok && x0ok) ? wy1 * wx0 * m : 0.f;
      float w11 = (y1ok && x1ok) ? wy1 * wx1 * m : 0.f;
      int y0c = min(max(y0, 0), H - 1), y1c = min(max(y1, 0), H - 1);
      int x0c = min(max(x0, 0), W - 1), x1c = min(max(x1, 0), W - 1);
      const float* p00 = xg + y0c * W + x0c;
      const float* p01 = xg + y0c * W + x1c;
      const float* p10 = xg + y1c * W + x0c;
      const float* p11 = xg + y1c * W + x1c;
      const float* wrow = wt + gk * Cg * O + og * OT;
#pragma unroll 4
      for (int c = 0; c < Cg; c++) {
        float v = p00[c * HW] * w00 + p01[c * HW] * w01 +
                  p10[c * HW] * w10 + p11[c * HW] * w11;
        const float* wr = wrow + c * O;
#pragma unroll
        for (int o = 0; o < OT; o++) acc[o] += v * wr[o];
      }
    }
  }

  float* ob = out + b * O * HW + og * OT * HW + pix;
#pragma unroll
  for (int o = 0; o < OT; o++) ob[o * HW] = acc[o];
}

// ---------------------------------------------------------------------------
extern "C" void kernel_launch(void* const* d_in, const int* in_sizes, int n_in,
                              void* d_out, int out_size, void* d_ws,
                              size_t ws_size, hipStream_t stream) {
  const float* x = (const float*)d_in[0];
  const float* w_main = (const float*)d_in[1];
  const float* w_off = (const float*)d_in[2];
  const float* b_off = (const float*)d_in[3];
  const float* w_mask = (const float*)d_in[4];
  const float* b_mask = (const float*)d_in[5];
  float* out = (float*)d_out;

  float* offs = (float*)d_ws;                 // B*36*HW floats
  float* msk = offs + BB * NOFF * HW;         // B*18*HW floats
  float* wcomb = msk + BB * NMSK * HW;        // 31104 floats
  float* wt = wcomb + C * K2 * NC;            // 36864 floats

  const int nprep = C * K2 * NC + OG * K2 * Cg * O;  // 67968
  prep_weights<<<(nprep + 255) / 256, 256, 0, stream>>>(w_main, w_off, w_mask,
                                                        wcomb, wt);
  conv_offmask<<<dim3(256, 3), 256, 0, stream>>>(x, wcomb, b_off, b_mask, offs,
                                                 msk);
  deform<<<dim3(256, 4), 256, 0, stream>>>(x, wt, offs, msk, out);
}

// Round 3
// 217.103 us; speedup vs baseline: 2.3605x; 2.3605x over previous
//
#include <hip/hip_runtime.h>
#include <math.h>

#define BB 4
#define C 64
#define O 64
#define H 128
#define W 128
#define OG 2
#define Cg 32
#define K2 9
#define HW (H*W)
#define NOFF 36
#define NMSK 18

typedef __bf16 bf16;
typedef bf16 bf16x8 __attribute__((ext_vector_type(8)));
typedef float f32x4 __attribute__((ext_vector_type(4)));

#define VSTR 296   /* val row stride in bf16 (288 + 8 pad); 592B = 37*16B aligned */
#define OSTR 59    /* offbuf row stride in dwords (54 + pad, picked for 2-way max) */

// ---------------------------------------------------------------------------
// NCHW fp32 -> NHWC bf16 transpose via LDS tile (64c x 64p per block).
// ---------------------------------------------------------------------------
__global__ __launch_bounds__(256) void transpose_nhwc(
    const float* __restrict__ x, bf16* __restrict__ xT) {
  __shared__ float tile[64][65];
  int tid = threadIdx.x;
  int b = blockIdx.x >> 8;
  int p0 = (blockIdx.x & 255) * 64;
#pragma unroll
  for (int it = 0; it < 16; ++it) {
    int c = it * 4 + (tid >> 6);
    tile[c][tid & 63] = x[((size_t)(b * C + c)) * HW + p0 + (tid & 63)];
  }
  __syncthreads();
#pragma unroll
  for (int it = 0; it < 16; ++it) {
    int pr = it * 4 + (tid >> 6);
    int c = tid & 63;
    xT[((size_t)(b * HW + p0 + pr)) * C + c] = (bf16)tile[c][pr];
  }
}

// ---------------------------------------------------------------------------
// Pre-swizzle weights into MFMA a-frag order:
//  frag[(ph*9+kk)*4+to][lane][j] = Wrow[m = to*16 + (lane&15)]
//                                      [u = kk*32 + (lane>>4)*8 + j]
// wfC (conv, ph = c-half): Wrow[o][u=c'*9+tap]; o<36 w_off, o<54 w_mask, else 0
// wfM (main, ph = group g): Wrow[o][u=c'*9+k] = w_main[o][g*32+c'][k]
// ---------------------------------------------------------------------------
__global__ __launch_bounds__(256) void prep_w(
    const float* __restrict__ w_main, const float* __restrict__ w_off,
    const float* __restrict__ w_mask, bf16* __restrict__ wfC,
    bf16* __restrict__ wfM) {
  int i = blockIdx.x * 256 + threadIdx.x;   // 0..73727
  int which = (i >= 36864);
  int ii = which ? i - 36864 : i;
  int j = ii & 7;
  int l = (ii >> 3) & 63;
  int rest = ii >> 9;
  int to = rest & 3;
  int kk = (rest >> 2) % 9;
  int ph = (rest >> 2) / 9;
  int m = to * 16 + (l & 15);
  int u = kk * 32 + (l >> 4) * 8 + j;   // 0..287
  int c1 = u / 9;
  int tap = u % 9;
  float v;
  if (!which) {
    int c = ph * 32 + c1;
    v = (m < NOFF) ? w_off[(m * C + c) * K2 + tap]
        : (m < 54) ? w_mask[((m - NOFF) * C + c) * K2 + tap]
                   : 0.f;
    wfC[ii] = (bf16)v;
  } else {
    v = w_main[(m * C + ph * 32 + c1) * K2 + tap];
    wfM[ii] = (bf16)v;
  }
}

// ---------------------------------------------------------------------------
// Fused kernel: per 64-pixel tile (one half-row): offset/mask conv (MFMA),
// bilinear gather from NHWC bf16 x, main einsum (MFMA), store.
// mfma_f32_16x16x32_bf16 layouts (learn_hip m89/m120 verified):
//   A: lane holds A[m=lane&15][k=(lane>>4)*8+j]
//   B: lane holds B[k=(lane>>4)*8+j][n=lane&15]
//   D: lane reg r holds D[m=(lane>>4)*4+r][n=lane&15]
// ---------------------------------------------------------------------------
__global__ __launch_bounds__(256, 3) void fused_deform(
    const bf16* __restrict__ xT, const bf16* __restrict__ wfC,
    const bf16* __restrict__ wfM, const float* __restrict__ b_off,
    const float* __restrict__ b_mask, float* __restrict__ out) {
  __shared__ bf16 val[64][VSTR];     // B^T tile: val[p][u], 37,888 B
  __shared__ float offbuf[64][OSTR]; // per-pixel offsets/masks, 15,104 B

  const int tid = threadIdx.x;
  const int lane = tid & 63;
  const int wv = tid >> 6;       // wave id = p-tile owner
  const int n16 = lane & 15;
  const int q4 = lane >> 4;
  const int half = lane >> 5;    // which pixel of the pair (gather)
  const int cl = lane & 31;      // channel-within-half (gather)

  const int b = blockIdx.x >> 8;
  const int ti = blockIdx.x & 255;
  const int h0 = ti >> 1;
  const int w0 = (ti & 1) * 64;
  const bf16* xb = xT + (size_t)b * HW * C;

  f32x4 accC[4] = {{0.f,0.f,0.f,0.f},{0.f,0.f,0.f,0.f},
                   {0.f,0.f,0.f,0.f},{0.f,0.f,0.f,0.f}};
  f32x4 accM[4] = {{0.f,0.f,0.f,0.f},{0.f,0.f,0.f,0.f},
                   {0.f,0.f,0.f,0.f},{0.f,0.f,0.f,0.f}};

  // ========== offset/mask conv: two c-halves of K=288 each ==========
#pragma unroll 1
  for (int ph = 0; ph < 2; ++ph) {
    if (ph) __syncthreads();           // val reuse vs previous GEMM reads
#pragma unroll 2
    for (int i = 0; i < 72; ++i) {     // (tap 0..8) x (pixel-pair 0..31)
      int idx = i * 4 + wv;
      int tap = idx >> 5;
      int p = ((idx & 31) << 1) + half;
      int yy = h0 + tap / 3 - 1;
      int xx = w0 + p + tap % 3 - 1;
      float v = 0.f;
      if ((unsigned)yy < (unsigned)H && (unsigned)xx < (unsigned)W)
        v = (float)xb[(size_t)((yy << 7) + xx) * C + ph * 32 + cl];
      val[p][cl * 9 + tap] = (bf16)v;
    }
    __syncthreads();
    const bf16* wb = wfC + ph * (9 * 4 * 64 * 8);
#pragma unroll
    for (int kk = 0; kk < 9; ++kk) {
      bf16x8 bfr = *(const bf16x8*)&val[wv * 16 + n16][kk * 32 + q4 * 8];
#pragma unroll
      for (int to = 0; to < 4; ++to) {
        bf16x8 afr = *(const bf16x8*)(wb + (size_t)((kk * 4 + to) * 64 + lane) * 8);
        accC[to] = __builtin_amdgcn_mfma_f32_16x16x32_bf16(afr, bfr, accC[to], 0, 0, 0);
      }
    }
  }
  // bias + sigmoid -> offbuf[p][o]  (wave owns p = wv*16 + n16)
  {
    int p = wv * 16 + n16;
#pragma unroll
    for (int to = 0; to < 4; ++to)
#pragma unroll
      for (int r = 0; r < 4; ++r) {
        int o = to * 16 + q4 * 4 + r;
        float a = accC[to][r];
        if (o < NOFF) {
          offbuf[p][o] = a + b_off[o];
        } else if (o < 54) {
          float s = a + b_mask[o - NOFF];
          offbuf[p][o] = 1.f / (1.f + __expf(-s));
        }
      }
  }
  __syncthreads();

  // ========== main deform: two groups of K=288 each ==========
#pragma unroll 1
  for (int g = 0; g < 2; ++g) {
    if (g) __syncthreads();
#pragma unroll 2
    for (int i = 0; i < 72; ++i) {
      int idx = i * 4 + wv;
      int tap = idx >> 5;
      int p = ((idx & 31) << 1) + half;
      int gk = g * 9 + tap;
      float offy = offbuf[p][2 * gk];
      float offx = offbuf[p][2 * gk + 1];
      float m = offbuf[p][NOFF + gk];
      float py = offy + (float)(h0 + tap / 3 - 1);
      float px = offx + (float)(w0 + p + tap % 3 - 1);
      float y0f = floorf(py), x0f = floorf(px);
      float wy1 = py - y0f, wx1 = px - x0f;
      float wy0 = 1.f - wy1, wx0 = 1.f - wx1;
      int y0 = (int)y0f, x0i = (int)x0f;
      int y1 = y0 + 1, x1 = x0i + 1;
      bool y0ok = (unsigned)y0 < (unsigned)H, y1ok = (unsigned)y1 < (unsigned)H;
      bool x0ok = (unsigned)x0i < (unsigned)W, x1ok = (unsigned)x1 < (unsigned)W;
      float w00 = (y0ok && x0ok) ? wy0 * wx0 * m : 0.f;
      float w01 = (y0ok && x1ok) ? wy0 * wx1 * m : 0.f;
      float w10 = (y1ok && x0ok) ? wy1 * wx0 * m : 0.f;
      float w11 = (y1ok && x1ok) ? wy1 * wx1 * m : 0.f;
      int y0c = min(max(y0, 0), H - 1), y1c = min(max(y1, 0), H - 1);
      int x0c = min(max(x0i, 0), W - 1), x1c = min(max(x1, 0), W - 1);
      const bf16* base = xb + g * 32 + cl;
      float v00 = (float)base[(size_t)((y0c << 7) + x0c) * C];
      float v01 = (float)base[(size_t)((y0c << 7) + x1c) * C];
      float v10 = (float)base[(size_t)((y1c << 7) + x0c) * C];
      float v11 = (float)base[(size_t)((y1c << 7) + x1c) * C];
      float v = v00 * w00 + v01 * w01 + v10 * w10 + v11 * w11;
      val[p][cl * 9 + tap] = (bf16)v;
    }
    __syncthreads();
    const bf16* wb = wfM + g * (9 * 4 * 64 * 8);
#pragma unroll
    for (int kk = 0; kk < 9; ++kk) {
      bf16x8 bfr = *(const bf16x8*)&val[wv * 16 + n16][kk * 32 + q4 * 8];
#pragma unroll
      for (int to = 0; to < 4; ++to) {
        bf16x8 afr = *(const bf16x8*)(wb + (size_t)((kk * 4 + to) * 64 + lane) * 8);
        accM[to] = __builtin_amdgcn_mfma_f32_16x16x32_bf16(afr, bfr, accM[to], 0, 0, 0);
      }
    }
  }

  // ========== epilogue: out[b][o][h0][w0+p] ==========
  {
    int p = wv * 16 + n16;
    float* ob = out + (size_t)b * O * HW + (h0 << 7) + w0 + p;
#pragma unroll
    for (int to = 0; to < 4; ++to)
#pragma unroll
      for (int r = 0; r < 4; ++r) {
        int o = to * 16 + q4 * 4 + r;
        ob[(size_t)o * HW] = accM[to][r];
      }
  }
}

// ---------------------------------------------------------------------------
extern "C" void kernel_launch(void* const* d_in, const int* in_sizes, int n_in,
                              void* d_out, int out_size, void* d_ws,
                              size_t ws_size, hipStream_t stream) {
  const float* x = (const float*)d_in[0];
  const float* w_main = (const float*)d_in[1];
  const float* w_off = (const float*)d_in[2];
  const float* b_off = (const float*)d_in[3];
  const float* w_mask = (const float*)d_in[4];
  const float* b_mask = (const float*)d_in[5];
  float* out = (float*)d_out;

  bf16* xT = (bf16*)d_ws;             // 4*16384*64 bf16 = 8.39 MB
  bf16* wfC = xT + (size_t)BB * HW * C;  // 36864 bf16
  bf16* wfM = wfC + 36864;               // 36864 bf16

  transpose_nhwc<<<1024, 256, 0, stream>>>(x, xT);
  prep_w<<<288, 256, 0, stream>>>(w_main, w_off, w_mask, wfC, wfM);
  fused_deform<<<1024, 256, 0, stream>>>(xT, wfC, wfM, b_off, b_mask, out);
}

// Round 4
// 130.634 us; speedup vs baseline: 3.9229x; 1.6619x over previous
//
#include <hip/hip_runtime.h>
#include <math.h>

#define BB 4
#define C 64
#define O 64
#define H 128
#define W 128
#define OG 2
#define Cg 32
#define K2 9
#define HW (H*W)
#define NOFF 36
#define NMSK 18

typedef __bf16 bf16;
typedef bf16 bf16x8 __attribute__((ext_vector_type(8)));
typedef float f32x4 __attribute__((ext_vector_type(4)));
typedef unsigned short u16x4 __attribute__((ext_vector_type(4)));

#define VSTR 288   /* val row stride in bf16; 576B ≡ 64 mod 128 -> 2-way-max banks */
#define BSTR 60    /* buf row stride in dwords (54 used + pad) */

__device__ inline unsigned short f2h_bits(float f) {
  _Float16 h = (_Float16)f;
  return __builtin_bit_cast(unsigned short, h);
}
__device__ inline float h2f(unsigned short u) {
  return (float)__builtin_bit_cast(_Float16, u);
}

// ---------------------------------------------------------------------------
// NCHW fp32 -> NHWC bf16 transpose via LDS tile (64c x 64p per block).
// ---------------------------------------------------------------------------
__global__ __launch_bounds__(256) void transpose_nhwc(
    const float* __restrict__ x, unsigned short* __restrict__ xT) {
  __shared__ float tile[64][65];
  int tid = threadIdx.x;
  int b = blockIdx.x >> 8;
  int p0 = (blockIdx.x & 255) * 64;
#pragma unroll
  for (int it = 0; it < 16; ++it) {
    int c = it * 4 + (tid >> 6);
    tile[c][tid & 63] = x[((size_t)(b * C + c)) * HW + p0 + (tid & 63)];
  }
  __syncthreads();
#pragma unroll
  for (int it = 0; it < 4; ++it) {
    int p = it * 16 + (tid >> 4);
    int cg = tid & 15;
    u16x4 o;
#pragma unroll
    for (int j = 0; j < 4; ++j) {
      bf16 t = (bf16)tile[cg * 4 + j][p];
      o[j] = __builtin_bit_cast(unsigned short, t);
    }
    *(u16x4*)&xT[((size_t)(b * HW + p0 + p)) * C + cg * 4] = o;
  }
}

// ---------------------------------------------------------------------------
// Pre-swizzle weights into MFMA a-frag order. K order: u = tap*32 + c'.
//  frag[(ph*9+kk)*4+to][lane][j] = Wrow[m = to*16+(lane&15)][u = kk*32+(lane>>4)*8+j]
// wfC (conv, ph = c-half): m<36 w_off, m<54 w_mask, else 0
// wfM (main, ph = group g): w_main[m][g*32+c'][tap]
// ---------------------------------------------------------------------------
__global__ __launch_bounds__(256) void prep_w(
    const float* __restrict__ w_main, const float* __restrict__ w_off,
    const float* __restrict__ w_mask, bf16* __restrict__ wfC,
    bf16* __restrict__ wfM) {
  int i = blockIdx.x * 256 + threadIdx.x;   // 0..73727
  int which = (i >= 36864);
  int ii = which ? i - 36864 : i;
  int j = ii & 7;
  int l = (ii >> 3) & 63;
  int rest = ii >> 9;
  int to = rest & 3;
  int kk = (rest >> 2) % 9;
  int ph = (rest >> 2) / 9;
  int m = to * 16 + (l & 15);
  int u = kk * 32 + (l >> 4) * 8 + j;   // 0..287
  int tap = u >> 5;                      // == kk
  int c1 = u & 31;
  float v;
  if (!which) {
    int c = ph * 32 + c1;
    v = (m < NOFF) ? w_off[(m * C + c) * K2 + tap]
        : (m < 54) ? w_mask[((m - NOFF) * C + c) * K2 + tap]
                   : 0.f;
    wfC[ii] = (bf16)v;
  } else {
    v = w_main[(m * C + ph * 32 + c1) * K2 + tap];
    wfM[ii] = (bf16)v;
  }
}

// ---------------------------------------------------------------------------
// Fused: conv(MFMA) -> bilinear precompute -> gather(vec8) -> main GEMM(MFMA).
// mfma_f32_16x16x32_bf16 layouts (m89/m120 verified):
//   A: lane holds A[m=lane&15][k=(lane>>4)*8+j]
//   B: lane holds B[k=(lane>>4)*8+j][n=lane&15]
//   D: reg r holds D[m=(lane>>4)*4+r][n=lane&15]
// LDS: val[64][288] bf16 (36,864B) + buf[64][60] dw (15,360B) = 52,224B
//   buf phase A: 54 floats (offsets+mask) per pixel
//   buf phase B (overlay): per gk: dw[2gk]={w00,w01}f16, dw[2gk+1]={w10,w11}f16,
//                          dw[36+gk]=packed coords (y0,x0,y1,x1 uchar)
// ---------------------------------------------------------------------------
__global__ __launch_bounds__(256, 3) void fused_deform(
    const bf16* __restrict__ xT, const bf16* __restrict__ wfC,
    const bf16* __restrict__ wfM, const float* __restrict__ b_off,
    const float* __restrict__ b_mask, float* __restrict__ out) {
  __shared__ bf16 val[64][VSTR];
  __shared__ unsigned int buf[64][BSTR];
  float* bufF = (float*)&buf[0][0];

  const int tid = threadIdx.x;
  const int lane = tid & 63;
  const int wv = tid >> 6;
  const int n16 = lane & 15;
  const int q4 = lane >> 4;
  const int chunk = tid & 3;      // 8-channel chunk (im2col/gather)
  const int pg = tid >> 2;        // pixel (im2col/gather), 0..63

  const int b = blockIdx.x >> 8;
  const int ti = blockIdx.x & 255;
  const int h0 = ti >> 1;
  const int w0 = (ti & 1) * 64;
  const bf16* xb = xT + (size_t)b * HW * C;

  bf16x8 zero8;
#pragma unroll
  for (int j = 0; j < 8; ++j) zero8[j] = (bf16)0.f;

  // ================= offset/mask conv: two c-halves of K=288 =================
  f32x4 accC[4] = {{0.f,0.f,0.f,0.f},{0.f,0.f,0.f,0.f},
                   {0.f,0.f,0.f,0.f},{0.f,0.f,0.f,0.f}};
#pragma unroll 1
  for (int ph = 0; ph < 2; ++ph) {
    if (ph) __syncthreads();
#pragma unroll
    for (int tap = 0; tap < 9; ++tap) {
      int yy = h0 + tap / 3 - 1;
      int xx = w0 + pg + tap % 3 - 1;
      bf16x8 v = zero8;
      if ((unsigned)yy < (unsigned)H) {
        int xc = min(max(xx, 0), W - 1);
        bf16x8 t = *(const bf16x8*)(xb + (size_t)((yy << 7) + xc) * C + ph * 32 + chunk * 8);
        if ((unsigned)xx < (unsigned)W) v = t;
      }
      *(bf16x8*)&val[pg][tap * 32 + chunk * 8] = v;
    }
    __syncthreads();
    const bf16* wb = wfC + (size_t)ph * (9 * 4 * 64 * 8);
#pragma unroll
    for (int kk = 0; kk < 9; ++kk) {
      bf16x8 bfr = *(const bf16x8*)&val[wv * 16 + n16][kk * 32 + q4 * 8];
#pragma unroll
      for (int to = 0; to < 4; ++to) {
        bf16x8 afr = *(const bf16x8*)(wb + (size_t)((kk * 4 + to) * 64 + lane) * 8);
        accC[to] = __builtin_amdgcn_mfma_f32_16x16x32_bf16(afr, bfr, accC[to], 0, 0, 0);
      }
    }
  }
  // epilogue: bias + sigmoid -> bufF[p][o]
  {
    int p = wv * 16 + n16;
#pragma unroll
    for (int to = 0; to < 4; ++to)
#pragma unroll
      for (int r = 0; r < 4; ++r) {
        int o = to * 16 + q4 * 4 + r;
        float a = accC[to][r];
        if (o < NOFF) {
          bufF[p * BSTR + o] = a + b_off[o];
        } else if (o < 54) {
          float s = a + b_mask[o - NOFF];
          bufF[p * BSTR + o] = 1.f / (1.f + __expf(-s));
        }
      }
  }
  __syncthreads();

  // ============== bilinear precompute: 1152 (p,gk) tasks ==============
  unsigned int rW0[5], rW1[5], rCo[5];
#pragma unroll
  for (int it = 0; it < 5; ++it) {
    int t = it * 256 + tid;
    if (t < 1152) {
      int p = t & 63;
      int gk = t >> 6;
      int g = gk / 9, tap = gk % 9;
      float offy = bufF[p * BSTR + 2 * gk];
      float offx = bufF[p * BSTR + 2 * gk + 1];
      float m = bufF[p * BSTR + NOFF + gk];
      float py = offy + (float)(h0 + tap / 3 - 1);
      float px = offx + (float)(w0 + p + tap % 3 - 1);
      float y0f = floorf(py), x0f = floorf(px);
      float wy1 = py - y0f, wx1 = px - x0f;
      float wy0 = 1.f - wy1, wx0 = 1.f - wx1;
      int y0 = (int)y0f, x0 = (int)x0f;
      int y1 = y0 + 1, x1 = x0 + 1;
      bool y0ok = (unsigned)y0 < (unsigned)H, y1ok = (unsigned)y1 < (unsigned)H;
      bool x0ok = (unsigned)x0 < (unsigned)W, x1ok = (unsigned)x1 < (unsigned)W;
      float w00 = (y0ok && x0ok) ? wy0 * wx0 * m : 0.f;
      float w01 = (y0ok && x1ok) ? wy0 * wx1 * m : 0.f;
      float w10 = (y1ok && x0ok) ? wy1 * wx0 * m : 0.f;
      float w11 = (y1ok && x1ok) ? wy1 * wx1 * m : 0.f;
      unsigned int y0c = (unsigned)min(max(y0, 0), H - 1);
      unsigned int y1c = (unsigned)min(max(y1, 0), H - 1);
      unsigned int x0c = (unsigned)min(max(x0, 0), W - 1);
      unsigned int x1c = (unsigned)min(max(x1, 0), W - 1);
      rW0[it] = (unsigned)f2h_bits(w00) | ((unsigned)f2h_bits(w01) << 16);
      rW1[it] = (unsigned)f2h_bits(w10) | ((unsigned)f2h_bits(w11) << 16);
      rCo[it] = y0c | (x0c << 8) | (y1c << 16) | (x1c << 24);
    }
  }
  __syncthreads();
#pragma unroll
  for (int it = 0; it < 5; ++it) {
    int t = it * 256 + tid;
    if (t < 1152) {
      int p = t & 63;
      int gk = t >> 6;
      buf[p][2 * gk] = rW0[it];
      buf[p][2 * gk + 1] = rW1[it];
      buf[p][NOFF + gk] = rCo[it];
    }
  }
  __syncthreads();

  // ================= main deform: two groups of K=288 =================
  f32x4 accM[4] = {{0.f,0.f,0.f,0.f},{0.f,0.f,0.f,0.f},
                   {0.f,0.f,0.f,0.f},{0.f,0.f,0.f,0.f}};
#pragma unroll 1
  for (int g = 0; g < 2; ++g) {
    if (g) __syncthreads();
    const bf16* bb = xb + g * 32 + chunk * 8;
#pragma unroll 3
    for (int tap = 0; tap < 9; ++tap) {
      int gk = g * 9 + tap;
      unsigned int wab = buf[pg][2 * gk];
      unsigned int wcd = buf[pg][2 * gk + 1];
      unsigned int pk = buf[pg][NOFF + gk];
      float w00 = h2f(wab & 0xffff), w01 = h2f(wab >> 16);
      float w10 = h2f(wcd & 0xffff), w11 = h2f(wcd >> 16);
      int r0 = (int)(pk & 255) << 7;
      int x0 = (int)((pk >> 8) & 255);
      int r1 = (int)((pk >> 16) & 255) << 7;
      int x1 = (int)(pk >> 24);
      bf16x8 v00 = *(const bf16x8*)(bb + (size_t)(r0 + x0) * C);
      bf16x8 v01 = *(const bf16x8*)(bb + (size_t)(r0 + x1) * C);
      bf16x8 v10 = *(const bf16x8*)(bb + (size_t)(r1 + x0) * C);
      bf16x8 v11 = *(const bf16x8*)(bb + (size_t)(r1 + x1) * C);
      bf16x8 res;
#pragma unroll
      for (int j = 0; j < 8; ++j) {
        float v = (float)v00[j] * w00 + (float)v01[j] * w01 +
                  (float)v10[j] * w10 + (float)v11[j] * w11;
        res[j] = (bf16)v;
      }
      *(bf16x8*)&val[pg][tap * 32 + chunk * 8] = res;
    }
    __syncthreads();
    const bf16* wb = wfM + (size_t)g * (9 * 4 * 64 * 8);
#pragma unroll
    for (int kk = 0; kk < 9; ++kk) {
      bf16x8 bfr = *(const bf16x8*)&val[wv * 16 + n16][kk * 32 + q4 * 8];
#pragma unroll
      for (int to = 0; to < 4; ++to) {
        bf16x8 afr = *(const bf16x8*)(wb + (size_t)((kk * 4 + to) * 64 + lane) * 8);
        accM[to] = __builtin_amdgcn_mfma_f32_16x16x32_bf16(afr, bfr, accM[to], 0, 0, 0);
      }
    }
  }

  // ================= epilogue: out[b][o][h0][w0+p] =================
  {
    int p = wv * 16 + n16;
    float* ob = out + (size_t)b * O * HW + (h0 << 7) + w0 + p;
#pragma unroll
    for (int to = 0; to < 4; ++to)
#pragma unroll
      for (int r = 0; r < 4; ++r) {
        int o = to * 16 + q4 * 4 + r;
        ob[(size_t)o * HW] = accM[to][r];
      }
  }
}

// ---------------------------------------------------------------------------
extern "C" void kernel_launch(void* const* d_in, const int* in_sizes, int n_in,
                              void* d_out, int out_size, void* d_ws,
                              size_t ws_size, hipStream_t stream) {
  const float* x = (const float*)d_in[0];
  const float* w_main = (const float*)d_in[1];
  const float* w_off = (const float*)d_in[2];
  const float* b_off = (const float*)d_in[3];
  const float* w_mask = (const float*)d_in[4];
  const float* b_mask = (const float*)d_in[5];
  float* out = (float*)d_out;

  bf16* xT = (bf16*)d_ws;                // 4*16384*64 bf16 = 8.39 MB
  bf16* wfC = xT + (size_t)BB * HW * C;  // 36864 bf16
  bf16* wfM = wfC + 36864;               // 36864 bf16

  transpose_nhwc<<<1024, 256, 0, stream>>>(x, (unsigned short*)xT);
  prep_w<<<288, 256, 0, stream>>>(w_main, w_off, w_mask, wfC, wfM);
  fused_deform<<<1024, 256, 0, stream>>>(xT, wfC, wfM, b_off, b_mask, out);
}